// Round 1
// baseline (794.185 us; speedup 1.0000x reference)
//
#include <hip/hip_runtime.h>

#define NN 100000
#define NE 1000000
#define DIN 64
#define DH 128

// workspace layout (floats):
// agg1[NN*64] | cnt[NN] | agg2[NN*2] | bnsum[128] | bnsumsq[128] | coefA[128] | coefC[128] | h[NN*128]
#define OFF_AGG1 0
#define OFF_CNT  (NN * DIN)
#define OFF_AGG2 (OFF_CNT + NN)
#define OFF_BNSUM (OFF_AGG2 + NN * 2)
#define OFF_BNSQ (OFF_BNSUM + DH)
#define OFF_CA   (OFF_BNSQ + DH)
#define OFF_CC   (OFF_CA + DH)
#define OFF_H    (OFF_CC + DH)

// ---------------- stage 1: scatter-mean of x over edges (one wave per edge) ----------------
__global__ __launch_bounds__(256) void k_scatter1(const float* __restrict__ x,
                                                  const int* __restrict__ src,
                                                  const int* __restrict__ dst,
                                                  float* __restrict__ agg,
                                                  float* __restrict__ cnt) {
    int wid = (blockIdx.x * 256 + threadIdx.x) >> 6;  // edge id
    int lane = threadIdx.x & 63;
    if (wid >= NE) return;
    int s = src[wid];
    int d = dst[wid];
    float v = x[(size_t)s * DIN + lane];
    atomicAdd(&agg[(size_t)d * DIN + lane], v);
    if (lane == 0) atomicAdd(&cnt[d], 1.0f);
}

// ---------------- stage 2: h = (agg/cnt)@W1l + x@W1r + b1, fused BN-stat partials ----------------
__global__ __launch_bounds__(256, 2) void k_layer1(const float* __restrict__ x,
                                                   const float* __restrict__ agg,
                                                   const float* __restrict__ cnt,
                                                   const float* __restrict__ W1l,
                                                   const float* __restrict__ W1r,
                                                   const float* __restrict__ b1,
                                                   float* __restrict__ h,
                                                   float* __restrict__ bnsum,
                                                   float* __restrict__ bnsq) {
    const int c = threadIdx.x & 127;   // output channel
    const int sub = threadIdx.x >> 7;  // which of the 2 nodes per block-iter

    // weight columns in registers: 128 VGPRs
    float wl[DIN], wr[DIN];
#pragma unroll
    for (int k = 0; k < DIN; ++k) {
        wl[k] = W1l[k * DH + c];
        wr[k] = W1r[k * DH + c];
    }
    const float bias = b1[c];

    __shared__ float sAgg[2][DIN];
    __shared__ float sX[2][DIN];
    __shared__ float sInv[2];

    float psum = 0.f, psumsq = 0.f;

    for (int base = blockIdx.x * 2; base < NN; base += gridDim.x * 2) {
        __syncthreads();  // previous-iteration reads done
        if (threadIdx.x < 128) {
            int nn = threadIdx.x >> 6, kk = threadIdx.x & 63;
            int nd = base + nn;
            sAgg[nn][kk] = (nd < NN) ? agg[(size_t)nd * DIN + kk] : 0.f;
            if (kk == 0) sInv[nn] = (nd < NN) ? 1.f / fmaxf(cnt[nd], 1.f) : 0.f;
        } else {
            int t = threadIdx.x - 128;
            int nn = t >> 6, kk = t & 63;
            int nd = base + nn;
            sX[nn][kk] = (nd < NN) ? x[(size_t)nd * DIN + kk] : 0.f;
        }
        __syncthreads();
        int node = base + sub;
        if (node < NN) {
            const float inv = sInv[sub];
            float acc = bias;
#pragma unroll
            for (int k = 0; k < DIN; ++k)
                acc += sAgg[sub][k] * inv * wl[k] + sX[sub][k] * wr[k];
            h[(size_t)node * DH + c] = acc;
            psum += acc;
            psumsq += acc * acc;
        }
    }

    // cross-half reduce in LDS, then one atomic per channel per block
    float* sR1 = &sAgg[0][0];  // 128 floats
    float* sR2 = &sX[0][0];    // 128 floats
    __syncthreads();
    if (sub == 1) { sR1[c] = psum; sR2[c] = psumsq; }
    __syncthreads();
    if (sub == 0) {
        atomicAdd(&bnsum[c], psum + sR1[c]);
        atomicAdd(&bnsq[c], psumsq + sR2[c]);
    }
}

// ---------------- stage 3: fold BN into per-channel affine (a, c) ----------------
__global__ void k_bnfin(const float* __restrict__ bnsum, const float* __restrict__ bnsq,
                        const float* __restrict__ gamma, const float* __restrict__ beta,
                        float* __restrict__ cA, float* __restrict__ cC) {
    int c = threadIdx.x;
    if (c < DH) {
        float mu = bnsum[c] * (1.f / NN);
        float var = bnsq[c] * (1.f / NN) - mu * mu;
        float rs = rsqrtf(var + 1e-5f);
        float a = rs * gamma[c];
        cA[c] = a;
        cC[c] = beta[c] - mu * a;
    }
}

// ---------------- stage 4: per-edge hbr[src]@W2l folded into scatter (2 atomics/edge) ----------------
__global__ __launch_bounds__(256) void k_scatter2(const float* __restrict__ h,
                                                  const int* __restrict__ src,
                                                  const int* __restrict__ dst,
                                                  const float* __restrict__ cA,
                                                  const float* __restrict__ cC,
                                                  const float* __restrict__ W2l,
                                                  float* __restrict__ agg2) {
    int wid = (blockIdx.x * 256 + threadIdx.x) >> 6;  // edge id
    int lane = threadIdx.x & 63;
    if (wid >= NE) return;
    int s = src[wid];
    int d = dst[wid];
    int c0 = lane * 2;
    float2 hv = *(const float2*)&h[(size_t)s * DH + c0];
    float hb0 = fmaxf(hv.x * cA[c0] + cC[c0], 0.f);
    float hb1 = fmaxf(hv.y * cA[c0 + 1] + cC[c0 + 1], 0.f);
    float p0 = hb0 * W2l[c0 * 2 + 0] + hb1 * W2l[c0 * 2 + 2];
    float p1 = hb0 * W2l[c0 * 2 + 1] + hb1 * W2l[c0 * 2 + 3];
#pragma unroll
    for (int off = 32; off > 0; off >>= 1) {
        p0 += __shfl_down(p0, off);
        p1 += __shfl_down(p1, off);
    }
    if (lane == 0) {
        atomicAdd(&agg2[(size_t)d * 2 + 0], p0);
        atomicAdd(&agg2[(size_t)d * 2 + 1], p1);
    }
}

// ---------------- stage 5: out = agg2/cnt + hbr@W2r + b2 (one wave per node) ----------------
__global__ __launch_bounds__(256) void k_final(const float* __restrict__ h,
                                               const float* __restrict__ agg2,
                                               const float* __restrict__ cnt,
                                               const float* __restrict__ cA,
                                               const float* __restrict__ cC,
                                               const float* __restrict__ W2r,
                                               const float* __restrict__ b2,
                                               float* __restrict__ out) {
    int wid = (blockIdx.x * 256 + threadIdx.x) >> 6;  // node id
    int lane = threadIdx.x & 63;
    if (wid >= NN) return;
    int c0 = lane * 2;
    float2 hv = *(const float2*)&h[(size_t)wid * DH + c0];
    float hb0 = fmaxf(hv.x * cA[c0] + cC[c0], 0.f);
    float hb1 = fmaxf(hv.y * cA[c0 + 1] + cC[c0 + 1], 0.f);
    float p0 = hb0 * W2r[c0 * 2 + 0] + hb1 * W2r[c0 * 2 + 2];
    float p1 = hb0 * W2r[c0 * 2 + 1] + hb1 * W2r[c0 * 2 + 3];
#pragma unroll
    for (int off = 32; off > 0; off >>= 1) {
        p0 += __shfl_down(p0, off);
        p1 += __shfl_down(p1, off);
    }
    if (lane == 0) {
        float inv = 1.f / fmaxf(cnt[wid], 1.f);
        out[(size_t)wid * 2 + 0] = agg2[(size_t)wid * 2 + 0] * inv + p0 + b2[0];
        out[(size_t)wid * 2 + 1] = agg2[(size_t)wid * 2 + 1] * inv + p1 + b2[1];
    }
}

extern "C" void kernel_launch(void* const* d_in, const int* in_sizes, int n_in,
                              void* d_out, int out_size, void* d_ws, size_t ws_size,
                              hipStream_t stream) {
    const float* x = (const float*)d_in[0];
    const int* ei = (const int*)d_in[1];
    const float* W1l = (const float*)d_in[2];
    const float* W1r = (const float*)d_in[3];
    const float* b1 = (const float*)d_in[4];
    const float* gamma = (const float*)d_in[5];
    const float* beta = (const float*)d_in[6];
    const float* W2l = (const float*)d_in[7];
    const float* W2r = (const float*)d_in[8];
    const float* b2 = (const float*)d_in[9];
    float* out = (float*)d_out;
    float* ws = (float*)d_ws;

    const int* src = ei;       // edge_index[0]
    const int* dst = ei + NE;  // edge_index[1]

    // zero agg1 | cnt | agg2 | bnsum | bnsumsq (contiguous prefix)
    hipMemsetAsync(ws, 0, (size_t)(OFF_BNSQ + DH) * sizeof(float), stream);

    k_scatter1<<<(NE + 3) / 4, 256, 0, stream>>>(x, src, dst, ws + OFF_AGG1, ws + OFF_CNT);
    k_layer1<<<512, 256, 0, stream>>>(x, ws + OFF_AGG1, ws + OFF_CNT, W1l, W1r, b1,
                                      ws + OFF_H, ws + OFF_BNSUM, ws + OFF_BNSQ);
    k_bnfin<<<1, 128, 0, stream>>>(ws + OFF_BNSUM, ws + OFF_BNSQ, gamma, beta,
                                   ws + OFF_CA, ws + OFF_CC);
    k_scatter2<<<(NE + 3) / 4, 256, 0, stream>>>(ws + OFF_H, src, dst, ws + OFF_CA,
                                                 ws + OFF_CC, W2l, ws + OFF_AGG2);
    k_final<<<(NN + 3) / 4, 256, 0, stream>>>(ws + OFF_H, ws + OFF_AGG2, ws + OFF_CNT,
                                              ws + OFF_CA, ws + OFF_CC, W2r, b2, out);
}

// Round 3
// 447.111 us; speedup vs baseline: 1.7763x; 1.7763x over previous
//
#include <hip/hip_runtime.h>

#define NN 100000
#define NE 1000000
#define DIN 64
#define DH 128
#define NSCAN 98  // ceil(NN/1024)

// ---- workspace layout (32-bit words) ----
// hist[NN] | bnsum[128] | bnsq[128] | cA[128] | cC[128] | offs[NN+1] | pad |
// csr_src[NE] | plr[NN*4 floats, float4-aligned] | h[NN*128]
#define OFF_HIST  0
#define OFF_BNSUM (NN)
#define OFF_BNSQ  (NN + 128)
#define OFF_CA    (NN + 256)
#define OFF_CC    (NN + 384)
#define OFF_OFFS  (NN + 512)
#define OFF_CSR   (OFF_OFFS + NN + 4)          // mult of 4
#define OFF_PLR   (OFF_CSR + NE)               // mult of 4 -> 16B aligned
#define OFF_H     (OFF_PLR + NN * 4)
// scan partials (98 ints) borrow the front of the h region (h written later).

// ---------------- CSR build ----------------
__global__ __launch_bounds__(256) void k_hist(const int* __restrict__ dst, int* __restrict__ hist) {
    int e = blockIdx.x * 256 + threadIdx.x;
    if (e < NE) atomicAdd(&hist[dst[e]], 1);
}

__global__ __launch_bounds__(1024) void k_scan1(const int* __restrict__ hist,
                                                int* __restrict__ offs, int* __restrict__ bsum) {
    __shared__ int tmp[1024];
    int t = threadIdx.x, idx = blockIdx.x * 1024 + t;
    int v = (idx < NN) ? hist[idx] : 0;
    int sum = v;
    tmp[t] = sum;
    __syncthreads();
    for (int off = 1; off < 1024; off <<= 1) {
        int o = (t >= off) ? tmp[t - off] : 0;
        __syncthreads();
        sum += o;
        tmp[t] = sum;
        __syncthreads();
    }
    if (idx < NN) offs[idx] = sum - v;  // local exclusive
    if (t == 1023) bsum[blockIdx.x] = sum;
}

__global__ void k_scan2(int* __restrict__ bsum) {
    if (threadIdx.x == 0) {
        int acc = 0;
        for (int i = 0; i < NSCAN; ++i) { int v = bsum[i]; bsum[i] = acc; acc += v; }
    }
}

__global__ __launch_bounds__(1024) void k_scan3(int* __restrict__ offs, const int* __restrict__ bsum) {
    int t = threadIdx.x, idx = blockIdx.x * 1024 + t;
    if (idx < NN) offs[idx] += bsum[blockIdx.x];
    if (blockIdx.x == 0 && t == 0) offs[NN] = NE;
}

__global__ __launch_bounds__(256) void k_reorder(const int* __restrict__ src, const int* __restrict__ dst,
                                                 const int* __restrict__ offs, int* __restrict__ hist,
                                                 int* __restrict__ csr) {
    int e = blockIdx.x * 256 + threadIdx.x;
    if (e >= NE) return;
    int d = dst[e];
    int old = atomicSub(&hist[d], 1);        // count..1
    csr[offs[d] + old - 1] = src[e];
}

// ---------------- fused agg1 + layer1 + BN partials ----------------
// block = 256 threads = 4 waves; 4 nodes per iteration.
// phase A: wave w gather-reduces node base+w's neighborhood (lane = input dim) -> sAgg (mean folded),
//          and loads x row -> sX.
// phase B: thread (c = tid&127, sub = tid>>7) computes channels c of nodes base+2*sub, base+2*sub+1.
__global__ __launch_bounds__(256, 2) void k_layer1(const float* __restrict__ x,
                                                   const int* __restrict__ offs,
                                                   const int* __restrict__ csr,
                                                   const float* __restrict__ W1l,
                                                   const float* __restrict__ W1r,
                                                   const float* __restrict__ b1,
                                                   float* __restrict__ h,
                                                   float* __restrict__ bnsum,
                                                   float* __restrict__ bnsq) {
    const int c = threadIdx.x & 127;
    const int sub = threadIdx.x >> 7;
    const int w = threadIdx.x >> 6;
    const int lane = threadIdx.x & 63;

    float wl[DIN], wr[DIN];
#pragma unroll
    for (int k = 0; k < DIN; ++k) {
        wl[k] = W1l[k * DH + c];
        wr[k] = W1r[k * DH + c];
    }
    const float bias = b1[c];

    __shared__ float sAgg[4][DIN];
    __shared__ float sX[4][DIN];

    float psum = 0.f, psq = 0.f;

    for (int base = blockIdx.x * 4; base < NN; base += gridDim.x * 4) {
        __syncthreads();
        int node = base + w;
        {
            int beg = offs[node];
            int deg = offs[node + 1] - beg;
            float acc = 0.f;
            for (int ch = 0; ch < deg; ch += 64) {
                int m = min(deg - ch, 64);
                int sv = (lane < m) ? csr[beg + ch + lane] : 0;
                int j = 0;
                for (; j + 8 <= m; j += 8) {
                    float a0 = x[(size_t)__shfl(sv, j + 0) * DIN + lane];
                    float a1 = x[(size_t)__shfl(sv, j + 1) * DIN + lane];
                    float a2 = x[(size_t)__shfl(sv, j + 2) * DIN + lane];
                    float a3 = x[(size_t)__shfl(sv, j + 3) * DIN + lane];
                    float a4 = x[(size_t)__shfl(sv, j + 4) * DIN + lane];
                    float a5 = x[(size_t)__shfl(sv, j + 5) * DIN + lane];
                    float a6 = x[(size_t)__shfl(sv, j + 6) * DIN + lane];
                    float a7 = x[(size_t)__shfl(sv, j + 7) * DIN + lane];
                    acc += ((a0 + a1) + (a2 + a3)) + ((a4 + a5) + (a6 + a7));
                }
                for (; j < m; ++j)
                    acc += x[(size_t)__shfl(sv, j) * DIN + lane];
            }
            sAgg[w][lane] = acc / fmaxf((float)deg, 1.f);
            sX[w][lane] = x[(size_t)node * DIN + lane];
        }
        __syncthreads();

        const int n0 = base + sub * 2, n1 = n0 + 1;
        float a0 = bias, a1 = bias;
#pragma unroll
        for (int k = 0; k < DIN; ++k) {
            a0 += sAgg[sub * 2][k] * wl[k] + sX[sub * 2][k] * wr[k];
            a1 += sAgg[sub * 2 + 1][k] * wl[k] + sX[sub * 2 + 1][k] * wr[k];
        }
        h[(size_t)n0 * DH + c] = a0;
        h[(size_t)n1 * DH + c] = a1;
        psum += a0 + a1;
        psq += a0 * a0 + a1 * a1;
    }

    // block-level BN partial reduce: 2 subs -> 1 atomic per channel
    float* r = &sAgg[0][0];  // 256 floats
    __syncthreads();
    if (sub == 1) { r[c] = psum; r[128 + c] = psq; }
    __syncthreads();
    if (sub == 0) {
        atomicAdd(&bnsum[c], psum + r[c]);
        atomicAdd(&bnsq[c], psq + r[128 + c]);
    }
}

// ---------------- fold BN into per-channel affine ----------------
__global__ void k_bnfin(const float* __restrict__ bnsum, const float* __restrict__ bnsq,
                        const float* __restrict__ gamma, const float* __restrict__ beta,
                        float* __restrict__ cA, float* __restrict__ cC) {
    int c = threadIdx.x;
    if (c < DH) {
        float mu = bnsum[c] * (1.f / NN);
        float var = bnsq[c] * (1.f / NN) - mu * mu;
        float a = rsqrtf(var + 1e-5f) * gamma[c];
        cA[c] = a;
        cC[c] = beta[c] - mu * a;
    }
}

// ---------------- per-node projection: plr[n] = {hb@W2l (2), hb@W2r (2)} ----------------
__global__ __launch_bounds__(256) void k_proj(const float* __restrict__ h,
                                              const float* __restrict__ cA,
                                              const float* __restrict__ cC,
                                              const float* __restrict__ W2l,
                                              const float* __restrict__ W2r,
                                              float4* __restrict__ plr) {
    int wid = (blockIdx.x * 256 + threadIdx.x) >> 6;  // node
    int lane = threadIdx.x & 63;
    if (wid >= NN) return;
    int c0 = lane * 2;
    float2 hv = *(const float2*)&h[(size_t)wid * DH + c0];
    float hb0 = fmaxf(hv.x * cA[c0] + cC[c0], 0.f);
    float hb1 = fmaxf(hv.y * cA[c0 + 1] + cC[c0 + 1], 0.f);
    float pl0 = hb0 * W2l[c0 * 2 + 0] + hb1 * W2l[c0 * 2 + 2];
    float pl1 = hb0 * W2l[c0 * 2 + 1] + hb1 * W2l[c0 * 2 + 3];
    float pr0 = hb0 * W2r[c0 * 2 + 0] + hb1 * W2r[c0 * 2 + 2];
    float pr1 = hb0 * W2r[c0 * 2 + 1] + hb1 * W2r[c0 * 2 + 3];
#pragma unroll
    for (int off = 32; off > 0; off >>= 1) {
        pl0 += __shfl_down(pl0, off);
        pl1 += __shfl_down(pl1, off);
        pr0 += __shfl_down(pr0, off);
        pr1 += __shfl_down(pr1, off);
    }
    if (lane == 0) plr[wid] = make_float4(pl0, pl1, pr0, pr1);
}

// ---------------- layer-2 aggregate + output (thread per node, CSR gather) ----------------
__global__ __launch_bounds__(256) void k_out(const float4* __restrict__ plr,
                                             const int* __restrict__ offs,
                                             const int* __restrict__ csr,
                                             const float* __restrict__ b2,
                                             float* __restrict__ out) {
    int d = blockIdx.x * 256 + threadIdx.x;
    if (d >= NN) return;
    int beg = offs[d];
    int deg = offs[d + 1] - beg;
    const float2* pl2 = (const float2*)plr;
    float s0 = 0.f, s1 = 0.f;
    for (int i = 0; i < deg; ++i) {
        int s = csr[beg + i];
        float2 p = pl2[(size_t)s * 2];  // {pl0, pl1}
        s0 += p.x;
        s1 += p.y;
    }
    float inv = 1.f / fmaxf((float)deg, 1.f);
    float4 me = plr[d];
    out[(size_t)d * 2 + 0] = s0 * inv + me.z + b2[0];
    out[(size_t)d * 2 + 1] = s1 * inv + me.w + b2[1];
}

extern "C" void kernel_launch(void* const* d_in, const int* in_sizes, int n_in,
                              void* d_out, int out_size, void* d_ws, size_t ws_size,
                              hipStream_t stream) {
    const float* x = (const float*)d_in[0];
    const int* ei = (const int*)d_in[1];
    const float* W1l = (const float*)d_in[2];
    const float* W1r = (const float*)d_in[3];
    const float* b1 = (const float*)d_in[4];
    const float* gamma = (const float*)d_in[5];
    const float* beta = (const float*)d_in[6];
    const float* W2l = (const float*)d_in[7];
    const float* W2r = (const float*)d_in[8];
    const float* b2 = (const float*)d_in[9];
    float* out = (float*)d_out;
    float* ws = (float*)d_ws;
    int* wsi = (int*)d_ws;

    const int* src = ei;
    const int* dst = ei + NE;

    int* hist = wsi + OFF_HIST;
    int* offs = wsi + OFF_OFFS;
    int* csr = wsi + OFF_CSR;
    int* bsum = wsi + OFF_H;  // borrow front of h region for 98 scan partials
    float* bnsum = ws + OFF_BNSUM;
    float* bnsq = ws + OFF_BNSQ;
    float* cA = ws + OFF_CA;
    float* cC = ws + OFF_CC;
    float4* plr = (float4*)(ws + OFF_PLR);
    float* h = ws + OFF_H;

    // zero hist + bn partials (contiguous prefix)
    hipMemsetAsync(ws, 0, (size_t)(NN + 256) * sizeof(float), stream);

    k_hist<<<(NE + 255) / 256, 256, 0, stream>>>(dst, hist);
    k_scan1<<<NSCAN, 1024, 0, stream>>>(hist, offs, bsum);
    k_scan2<<<1, 64, 0, stream>>>(bsum);
    k_scan3<<<NSCAN, 1024, 0, stream>>>(offs, bsum);
    k_reorder<<<(NE + 255) / 256, 256, 0, stream>>>(src, dst, offs, hist, csr);
    k_layer1<<<1024, 256, 0, stream>>>(x, offs, csr, W1l, W1r, b1, h, bnsum, bnsq);
    k_bnfin<<<1, 128, 0, stream>>>(bnsum, bnsq, gamma, beta, cA, cC);
    k_proj<<<(NN + 3) / 4, 256, 0, stream>>>(h, cA, cC, W2l, W2r, plr);
    k_out<<<(NN + 255) / 256, 256, 0, stream>>>(plr, offs, csr, b2, out);
}

// Round 4
// 386.463 us; speedup vs baseline: 2.0550x; 1.1569x over previous
//
#include <hip/hip_runtime.h>

#define NN 100000
#define NE 1000000
#define DIN 64
#define DH 128
#define NSCAN 98  // ceil(NN/1024)

// ---- workspace layout (32-bit words) ----
// hist[NN] | bnsum[128] | bnsq[128] | cA[128] | cC[128] | offs[NN+1] | pad |
// csr_src[NE] | plr[NN*4] | h[NN*128]  (agg lives in h[n][0:64) between k_agg and k_mm)
#define OFF_HIST  0
#define OFF_BNSUM (NN)
#define OFF_BNSQ  (NN + 128)
#define OFF_CA    (NN + 256)
#define OFF_CC    (NN + 384)
#define OFF_OFFS  (NN + 512)
#define OFF_CSR   (OFF_OFFS + NN + 4)
#define OFF_PLR   (OFF_CSR + NE)
#define OFF_H     (OFF_PLR + NN * 4)
// scan partials (98 ints) borrow the front of the plr region (plr written later).

// ---------------- CSR build ----------------
__global__ __launch_bounds__(256) void k_hist(const int* __restrict__ dst, int* __restrict__ hist) {
    int e = blockIdx.x * 256 + threadIdx.x;
    if (e < NE) atomicAdd(&hist[dst[e]], 1);
}

__global__ __launch_bounds__(1024) void k_scan1(const int* __restrict__ hist,
                                                int* __restrict__ offs, int* __restrict__ bsum) {
    __shared__ int tmp[1024];
    int t = threadIdx.x, idx = blockIdx.x * 1024 + t;
    int v = (idx < NN) ? hist[idx] : 0;
    int sum = v;
    tmp[t] = sum;
    __syncthreads();
    for (int off = 1; off < 1024; off <<= 1) {
        int o = (t >= off) ? tmp[t - off] : 0;
        __syncthreads();
        sum += o;
        tmp[t] = sum;
        __syncthreads();
    }
    if (idx < NN) offs[idx] = sum - v;  // local exclusive
    if (t == 1023) bsum[blockIdx.x] = sum;
}

__global__ void k_scan2(int* __restrict__ bsum) {
    if (threadIdx.x == 0) {
        int acc = 0;
        for (int i = 0; i < NSCAN; ++i) { int v = bsum[i]; bsum[i] = acc; acc += v; }
    }
}

__global__ __launch_bounds__(1024) void k_scan3(int* __restrict__ offs, const int* __restrict__ bsum) {
    int t = threadIdx.x, idx = blockIdx.x * 1024 + t;
    if (idx < NN) offs[idx] += bsum[blockIdx.x];
    if (blockIdx.x == 0 && t == 0) offs[NN] = NE;
}

__global__ __launch_bounds__(256) void k_reorder(const int* __restrict__ src, const int* __restrict__ dst,
                                                 const int* __restrict__ offs, int* __restrict__ hist,
                                                 int* __restrict__ csr) {
    int e = blockIdx.x * 256 + threadIdx.x;
    if (e >= NE) return;
    int d = dst[e];
    int old = atomicSub(&hist[d], 1);  // count..1
    csr[offs[d] + old - 1] = src[e];
}

// ---------------- agg: CSR gather-mean, wave per node, max TLP ----------------
// writes mean into h[node][0:64) (lower half of the h row; k_mm consumes then overwrites)
__global__ __launch_bounds__(256) void k_agg(const float* __restrict__ x,
                                             const int* __restrict__ offs,
                                             const int* __restrict__ csr,
                                             float* __restrict__ h) {
    int wid = (blockIdx.x * 256 + threadIdx.x) >> 6;  // node
    int lane = threadIdx.x & 63;
    if (wid >= NN) return;
    int beg = offs[wid];
    int deg = offs[wid + 1] - beg;
    float acc = 0.f;
    for (int ch = 0; ch < deg; ch += 64) {
        int m = min(deg - ch, 64);
        int sv = (lane < m) ? csr[beg + ch + lane] : 0;
        int j = 0;
        for (; j + 8 <= m; j += 8) {
            float a0 = x[(size_t)__shfl(sv, j + 0) * DIN + lane];
            float a1 = x[(size_t)__shfl(sv, j + 1) * DIN + lane];
            float a2 = x[(size_t)__shfl(sv, j + 2) * DIN + lane];
            float a3 = x[(size_t)__shfl(sv, j + 3) * DIN + lane];
            float a4 = x[(size_t)__shfl(sv, j + 4) * DIN + lane];
            float a5 = x[(size_t)__shfl(sv, j + 5) * DIN + lane];
            float a6 = x[(size_t)__shfl(sv, j + 6) * DIN + lane];
            float a7 = x[(size_t)__shfl(sv, j + 7) * DIN + lane];
            acc += ((a0 + a1) + (a2 + a3)) + ((a4 + a5) + (a6 + a7));
        }
        for (; j < m; ++j)
            acc += x[(size_t)__shfl(sv, j) * DIN + lane];
    }
    h[(size_t)wid * DH + lane] = acc / fmaxf((float)deg, 1.f);
}

// ---------------- dense dual-GEMM: h = agg@W1l + x@W1r + b1, BN partials ----------------
// 256 threads: c = tid&127 owns output channel c (weights in regs), sub = tid>>7 owns 16 of
// the 32 tile nodes. LDS compute reads are wave-uniform (broadcast, conflict-free).
__global__ __launch_bounds__(256, 2) void k_mm(const float* __restrict__ x,
                                               const float* __restrict__ W1l,
                                               const float* __restrict__ W1r,
                                               const float* __restrict__ b1,
                                               float* h,  // in: agg at [n][0:64); out: full rows
                                               float* __restrict__ bnsum,
                                               float* __restrict__ bnsq) {
    const int c = threadIdx.x & 127;
    const int sub = threadIdx.x >> 7;

    float wl[DIN], wr[DIN];
#pragma unroll
    for (int k = 0; k < DIN; ++k) {
        wl[k] = W1l[k * DH + c];
        wr[k] = W1r[k * DH + c];
    }
    const float bias = b1[c];

    __shared__ __align__(16) float sA[32][DIN];
    __shared__ __align__(16) float sX[32][DIN];

    float psum = 0.f, psq = 0.f;

    for (int base = blockIdx.x * 32; base < NN; base += gridDim.x * 32) {
        __syncthreads();  // prior-iter LDS reads done
#pragma unroll
        for (int i = 0; i < 2; ++i) {
            int f = threadIdx.x + i * 256;  // 0..511 float4 slots
            int row = f >> 4, col = (f & 15) * 4;
            *(float4*)&sA[row][col] = *(const float4*)&h[(size_t)(base + row) * DH + col];
            *(float4*)&sX[row][col] = *(const float4*)&x[(size_t)(base + row) * DIN + col];
        }
        __syncthreads();

        const int nb = sub * 16;
#pragma unroll
        for (int n = 0; n < 16; ++n) {
            float acc = bias;
#pragma unroll
            for (int kk = 0; kk < DIN; kk += 4) {
                float4 a4 = *(const float4*)&sA[nb + n][kk];
                float4 x4 = *(const float4*)&sX[nb + n][kk];
                acc += a4.x * wl[kk] + a4.y * wl[kk + 1] + a4.z * wl[kk + 2] + a4.w * wl[kk + 3];
                acc += x4.x * wr[kk] + x4.y * wr[kk + 1] + x4.z * wr[kk + 2] + x4.w * wr[kk + 3];
            }
            h[(size_t)(base + nb + n) * DH + c] = acc;
            psum += acc;
            psq += acc * acc;
        }
    }

    // BN partial reduce: 2 subs -> 1 atomic per channel
    float* rr = &sA[0][0];
    __syncthreads();
    if (sub == 1) { rr[c] = psum; rr[128 + c] = psq; }
    __syncthreads();
    if (sub == 0) {
        atomicAdd(&bnsum[c], psum + rr[c]);
        atomicAdd(&bnsq[c], psq + rr[128 + c]);
    }
}

// ---------------- fold BN into per-channel affine ----------------
__global__ void k_bnfin(const float* __restrict__ bnsum, const float* __restrict__ bnsq,
                        const float* __restrict__ gamma, const float* __restrict__ beta,
                        float* __restrict__ cA, float* __restrict__ cC) {
    int c = threadIdx.x;
    if (c < DH) {
        float mu = bnsum[c] * (1.f / NN);
        float var = bnsq[c] * (1.f / NN) - mu * mu;
        float a = rsqrtf(var + 1e-5f) * gamma[c];
        cA[c] = a;
        cC[c] = beta[c] - mu * a;
    }
}

// ---------------- per-node projection: plr[n] = {hb@W2l (2), hb@W2r (2)} ----------------
__global__ __launch_bounds__(256) void k_proj(const float* __restrict__ h,
                                              const float* __restrict__ cA,
                                              const float* __restrict__ cC,
                                              const float* __restrict__ W2l,
                                              const float* __restrict__ W2r,
                                              float4* __restrict__ plr) {
    int wid = (blockIdx.x * 256 + threadIdx.x) >> 6;  // node
    int lane = threadIdx.x & 63;
    if (wid >= NN) return;
    int c0 = lane * 2;
    float2 hv = *(const float2*)&h[(size_t)wid * DH + c0];
    float hb0 = fmaxf(hv.x * cA[c0] + cC[c0], 0.f);
    float hb1 = fmaxf(hv.y * cA[c0 + 1] + cC[c0 + 1], 0.f);
    float pl0 = hb0 * W2l[c0 * 2 + 0] + hb1 * W2l[c0 * 2 + 2];
    float pl1 = hb0 * W2l[c0 * 2 + 1] + hb1 * W2l[c0 * 2 + 3];
    float pr0 = hb0 * W2r[c0 * 2 + 0] + hb1 * W2r[c0 * 2 + 2];
    float pr1 = hb0 * W2r[c0 * 2 + 1] + hb1 * W2r[c0 * 2 + 3];
#pragma unroll
    for (int off = 32; off > 0; off >>= 1) {
        pl0 += __shfl_down(pl0, off);
        pl1 += __shfl_down(pl1, off);
        pr0 += __shfl_down(pr0, off);
        pr1 += __shfl_down(pr1, off);
    }
    if (lane == 0) plr[wid] = make_float4(pl0, pl1, pr0, pr1);
}

// ---------------- layer-2 aggregate + output (thread per node, CSR gather) ----------------
__global__ __launch_bounds__(256) void k_out(const float4* __restrict__ plr,
                                             const int* __restrict__ offs,
                                             const int* __restrict__ csr,
                                             const float* __restrict__ b2,
                                             float* __restrict__ out) {
    int d = blockIdx.x * 256 + threadIdx.x;
    if (d >= NN) return;
    int beg = offs[d];
    int deg = offs[d + 1] - beg;
    const float2* pl2 = (const float2*)plr;
    float s0 = 0.f, s1 = 0.f;
    for (int i = 0; i < deg; ++i) {
        int s = csr[beg + i];
        float2 p = pl2[(size_t)s * 2];  // {pl0, pl1}
        s0 += p.x;
        s1 += p.y;
    }
    float inv = 1.f / fmaxf((float)deg, 1.f);
    float4 me = plr[d];
    out[(size_t)d * 2 + 0] = s0 * inv + me.z + b2[0];
    out[(size_t)d * 2 + 1] = s1 * inv + me.w + b2[1];
}

extern "C" void kernel_launch(void* const* d_in, const int* in_sizes, int n_in,
                              void* d_out, int out_size, void* d_ws, size_t ws_size,
                              hipStream_t stream) {
    const float* x = (const float*)d_in[0];
    const int* ei = (const int*)d_in[1];
    const float* W1l = (const float*)d_in[2];
    const float* W1r = (const float*)d_in[3];
    const float* b1 = (const float*)d_in[4];
    const float* gamma = (const float*)d_in[5];
    const float* beta = (const float*)d_in[6];
    const float* W2l = (const float*)d_in[7];
    const float* W2r = (const float*)d_in[8];
    const float* b2 = (const float*)d_in[9];
    float* out = (float*)d_out;
    float* ws = (float*)d_ws;
    int* wsi = (int*)d_ws;

    const int* src = ei;
    const int* dst = ei + NE;

    int* hist = wsi + OFF_HIST;
    int* offs = wsi + OFF_OFFS;
    int* csr = wsi + OFF_CSR;
    int* bsum = wsi + OFF_PLR;  // scan partials borrow plr front (consumed before k_proj)
    float* bnsum = ws + OFF_BNSUM;
    float* bnsq = ws + OFF_BNSQ;
    float* cA = ws + OFF_CA;
    float* cC = ws + OFF_CC;
    float4* plr = (float4*)(ws + OFF_PLR);
    float* h = ws + OFF_H;

    // zero hist + bn partials (contiguous prefix)
    hipMemsetAsync(ws, 0, (size_t)(NN + 256) * sizeof(float), stream);

    k_hist<<<(NE + 255) / 256, 256, 0, stream>>>(dst, hist);
    k_scan1<<<NSCAN, 1024, 0, stream>>>(hist, offs, bsum);
    k_scan2<<<1, 64, 0, stream>>>(bsum);
    k_scan3<<<NSCAN, 1024, 0, stream>>>(offs, bsum);
    k_reorder<<<(NE + 255) / 256, 256, 0, stream>>>(src, dst, offs, hist, csr);
    k_agg<<<(NN * 64 + 255) / 256, 256, 0, stream>>>(x, offs, csr, h);
    k_mm<<<1024, 256, 0, stream>>>(x, W1l, W1r, b1, h, bnsum, bnsq);
    k_bnfin<<<1, 128, 0, stream>>>(bnsum, bnsq, gamma, beta, cA, cC);
    k_proj<<<(NN + 3) / 4, 256, 0, stream>>>(h, cA, cC, W2l, W2r, plr);
    k_out<<<(NN + 255) / 256, 256, 0, stream>>>(plr, offs, csr, b2, out);
}